// Round 10
// baseline (156.775 us; speedup 1.0000x reference)
//
#include <hip/hip_runtime.h>
#include <math.h>

#define NV 65536
#define NE 4096
#define NP 4096
#define NT 512
#define NB 32              // y-buckets
#define CAP 4096           // per-bucket capacity (worst observed ~2200 for this input)
#define SENTF 1000000000.0f
#define BIGF 1e30f

// ---------------- wave(64) reduction helpers ----------------
__device__ __forceinline__ float waveMinF(float v) {
    #pragma unroll
    for (int o = 32; o; o >>= 1) v = fminf(v, __shfl_xor(v, o, 64));
    return v;
}
__device__ __forceinline__ float waveMaxF(float v) {
    #pragma unroll
    for (int o = 32; o; o >>= 1) v = fmaxf(v, __shfl_xor(v, o, 64));
    return v;
}
__device__ __forceinline__ int waveSumI(int v) {
    #pragma unroll
    for (int o = 32; o; o >>= 1) v += __shfl_xor(v, o, 64);
    return v;
}
__device__ __forceinline__ int waveMinI(int v) {
    #pragma unroll
    for (int o = 32; o; o >>= 1) v = min(v, __shfl_xor(v, o, 64));
    return v;
}

// ---------------- kernel 1: edge params + table repack + y-bucket fill ----------------
__global__ void prep_kernel(const float* __restrict__ verts,
                            const int*   __restrict__ edges,
                            const float* __restrict__ tab,
                            float*  __restrict__ ea,   float* __restrict__ eb,
                            float4* __restrict__ pk14, float4* __restrict__ tb4,
                            float4* __restrict__ bk4,  int* __restrict__ cnt) {
    int e = blockIdx.x * blockDim.x + threadIdx.x;
    if (e < NT) {
        const float* r = tab + 7 * e;
        tb4[e] = make_float4(r[3], r[4], r[5], r[6]);
    }
    if (e >= NE) return;
    int i0 = edges[2 * e + 0];
    int i1 = edges[2 * e + 1];
    float x0 = verts[3 * i0 + 0], y0 = verts[3 * i0 + 1];
    float x1 = verts[3 * i1 + 0], y1 = verts[3 * i1 + 1];
    float a = (y0 - y1) / (x0 - x1);
    float b = y0 - a * x0;
    ea[e] = a; eb[e] = b;
    float xmn = fminf(x0, x1), xmx = fmaxf(x0, x1);
    float ymn = fminf(y0, y1), ymx = fmaxf(y0, y1);
    pk14[e] = make_float4(xmn, xmx, a, b);

    // y-bucket fill: edge goes into every bucket its (ymn,ymx) overlaps.
    float4 v = make_float4(ymn, ymx, 1.0f / a, b);
    int b0 = (int)fminf(fmaxf(ymn * (float)NB, 0.f), (float)(NB - 1));
    int b1 = (int)fminf(fmaxf(ymx * (float)NB, 0.f), (float)(NB - 1));
    for (int k = b0; k <= b1; ++k) {
        int s = atomicAdd(&cnt[k], 1);
        if (s < CAP) bk4[k * CAP + s] = v;   // guard never triggers for this input
    }
}

// ---------------- kernel 2: one wave per point, bucket-pruned phase 2 ----------------
// 1024 blocks x 256 thr = 4 independent waves; NO barriers, no cross-wave folds.
__global__ __launch_bounds__(256) void point_kernel(
        const float*  __restrict__ verts,
        const int*    __restrict__ listAll,
        const float*  __restrict__ ea,   const float*  __restrict__ eb,
        const float4* __restrict__ pk14, const float4* __restrict__ bk4,
        const int*    __restrict__ cnt,  const float4* __restrict__ tb4,
        float* __restrict__ mOut, int* __restrict__ vOut) {
    const int lane = threadIdx.x & 63;
    const int w    = threadIdx.x >> 6;      // 0..3
    const int p    = blockIdx.x * 4 + w;

    int   vi = listAll[p];
    float px = verts[3 * vi + 0];
    float py = verts[3 * vi + 1];

    // ---- phase 1: first edge with px strictly inside (xmn, xmx) — early exit.
    // Hits can only exist in the break iteration, so the winning lane (mi & 63)
    // still holds that edge's (a,b) in q4 -> broadcast via shfl, no extra loads.
    int minIdx = NE;
    float4 q4 = make_float4(0.f, 0.f, 0.f, 0.f);
    for (int it = 0; it < NE / 64; ++it) {
        int e = it * 64 + lane;
        q4 = pk14[e];
        bool hit = (px > q4.x) && (px < q4.y);
        if (hit) minIdx = e;
        if (__any(hit)) break;
    }
    int mi = waveMinI(minIdx);
    float a_, b_;
    if (mi < NE) {
        a_ = __shfl(q4.z, mi & 63, 64);
        b_ = __shfl(q4.w, mi & 63, 64);
    } else {                                  // no edge straddles px
        a_ = ea[NE - 1]; b_ = eb[NE - 1];
    }
    float exposeY = a_ * px + b_;             // identical arithmetic to reference
    float L1 = fabsf(py - exposeY);
    float cy = 0.5f * (py + exposeY);
    float cx = px;

    // ---- phase 2: scan only bucket(cy) ----
    float kf = fminf(fmaxf(cy * (float)NB, 0.f), (float)(NB - 1));  // NaN-safe clamp
    int   k  = (int)kf;                        // wave-uniform
    int   len = cnt[k];
    if (len > CAP) len = CAP;
    const float4* bl = bk4 + k * CAP;

    int   nAcc = 0, hasS = 0, hasI = 0;
    float xallmx = -SENTF, xallmn = SENTF;
    float xs = SENTF, xinf = -SENTF;
    for (int i = lane; i < len; i += 64) {
        float4 q = bl[i];                      // (ymn, ymx, 1/a, b)
        bool  c  = (cy > q.x) && (cy < q.y);
        float xi = (cy - q.w) * q.z;           // identical arithmetic to validated path
        nAcc += c ? 1 : 0;
        xallmx = fmaxf(xallmx, c ? xi : -SENTF);
        xallmn = fminf(xallmn, c ? xi :  SENTF);
        bool sp  = c && (xi >= cx);
        bool in_ = c && (xi <  cx);
        xs   = fminf(xs,   sp  ? xi :  SENTF);
        xinf = fmaxf(xinf, in_ ? xi : -SENTF);
        hasS |= sp ? 1 : 0;
        hasI |= in_ ? 1 : 0;
    }
    int packed = nAcc | (hasS << 16) | (hasI << 24);   // n<=4096, hasS/I sums <=64
    packed = waveSumI(packed);
    xallmx = waveMaxF(xallmx);
    xallmn = waveMinF(xallmn);
    xs     = waveMinF(xs);
    xinf   = waveMaxF(xinf);
    int n  = packed & 0xFFFF;
    int hS = (packed >> 16) & 0xFF;
    int hI = (packed >> 24) & 0xFF;

    bool valid = (n == 2) || ((n > 2) && (hS > 0) && (hI > 0));
    float dx = (n == 2) ? (xallmx - xallmn) : (xs - xinf);
    float L2 = fabsf(dx);
    float d1 = fabsf(cy - 1.0f);
    float d2 = fabsf(px - 1.0f);

    // ---- table min (validated float4 path) ----
    float pm = INFINITY;
    #pragma unroll
    for (int kk = 0; kk < NT / 64; ++kk) {
        float4 r = tb4[kk * 64 + lane];
        float al = fabsf(L1 - r.x) + fabsf(L2 - r.y) +
                   fabsf(d1 - r.z) + fabsf(d2 - r.w);
        pm = fminf(pm, al);
    }
    pm = waveMinF(pm);

    if (lane == 0) {
        mOut[p] = valid ? pm : BIGF;
        vOut[p] = valid ? 1 : 0;
    }
}

// ---------------- kernel 3: cummin + masked sum (validated) ----------------
__global__ __launch_bounds__(1024) void scan_kernel(const float* __restrict__ m,
                                                    const int*   __restrict__ valid,
                                                    float* __restrict__ out) {
    __shared__ float wAgg[16];
    __shared__ float wSum[16];
    int t = threadIdx.x;
    int lane = t & 63, wid = t >> 6;

    float v[4]; int vl[4];
    #pragma unroll
    for (int j = 0; j < 4; j++) { v[j] = m[4 * t + j]; vl[j] = valid[4 * t + j]; }
    float cmin = fminf(fminf(v[0], v[1]), fminf(v[2], v[3]));

    float inc = cmin;
    #pragma unroll
    for (int o = 1; o < 64; o <<= 1) {
        float u = __shfl_up(inc, o, 64);
        if (lane >= o) inc = fminf(inc, u);
    }
    if (lane == 63) wAgg[wid] = inc;
    __syncthreads();

    float wavePrefix = INFINITY;
    for (int i = 0; i < wid; i++) wavePrefix = fminf(wavePrefix, wAgg[i]);
    float excl = __shfl_up(inc, 1, 64);
    if (lane == 0) excl = INFINITY;
    float run = fminf(wavePrefix, excl);

    float sum = 0.0f;
    #pragma unroll
    for (int j = 0; j < 4; j++) {
        run = fminf(run, v[j]);
        if (vl[j]) sum += run;
    }
    #pragma unroll
    for (int o = 32; o; o >>= 1) sum += __shfl_xor(sum, o, 64);
    if (lane == 0) wSum[wid] = sum;
    __syncthreads();
    if (t == 0) {
        float s = 0.0f;
        for (int i = 0; i < 16; i++) s += wSum[i];
        out[0] = s;
    }
}

extern "C" void kernel_launch(void* const* d_in, const int* in_sizes, int n_in,
                              void* d_out, int out_size, void* d_ws, size_t ws_size,
                              hipStream_t stream) {
    const float* verts   = (const float*)d_in[0];
    const float* tab     = (const float*)d_in[1];
    const int*   edges   = (const int*)d_in[2];
    const int*   listAll = (const int*)d_in[3];

    char* ws = (char*)d_ws;
    float4* bk4  = (float4*)ws;                   ws += (size_t)NB * CAP * sizeof(float4); // 2 MB
    float4* pk14 = (float4*)ws;                   ws += NE * sizeof(float4);
    float4* tb4  = (float4*)ws;                   ws += NT * sizeof(float4);
    float*  ea   = (float*)ws;                    ws += NE * sizeof(float);
    float*  eb   = (float*)ws;                    ws += NE * sizeof(float);
    float*  mArr = (float*)ws;                    ws += NP * sizeof(float);
    int*    vArr = (int*)ws;                      ws += NP * sizeof(int);
    int*    cnt  = (int*)ws;

    hipMemsetAsync(cnt, 0, NB * sizeof(int), stream);   // capturable memset node
    prep_kernel<<<(NE + 255) / 256, 256, 0, stream>>>(verts, edges, tab,
                                                      ea, eb, pk14, tb4, bk4, cnt);
    point_kernel<<<NP / 4, 256, 0, stream>>>(verts, listAll,
                                             ea, eb, pk14, bk4, cnt, tb4,
                                             mArr, vArr);
    scan_kernel<<<1, 1024, 0, stream>>>(mArr, vArr, (float*)d_out);
}

// Round 11
// 27.846 us; speedup vs baseline: 5.6301x; 5.6301x over previous
//
#include <hip/hip_runtime.h>
#include <math.h>

#define NV 65536
#define NE 4096
#define NP 4096
#define NT 512
#define NPB 8              // points per block
#define HALF 2048          // edges per half
#define SENTF 1000000000.0f
#define BIGF 1e30f

// ---------------- wave(64) reduction helpers ----------------
__device__ __forceinline__ float waveMinF(float v) {
    #pragma unroll
    for (int o = 32; o; o >>= 1) v = fminf(v, __shfl_xor(v, o, 64));
    return v;
}
__device__ __forceinline__ float waveMaxF(float v) {
    #pragma unroll
    for (int o = 32; o; o >>= 1) v = fmaxf(v, __shfl_xor(v, o, 64));
    return v;
}
__device__ __forceinline__ int waveSumI(int v) {
    #pragma unroll
    for (int o = 32; o; o >>= 1) v += __shfl_xor(v, o, 64);
    return v;
}
__device__ __forceinline__ int waveMinI(int v) {
    #pragma unroll
    for (int o = 32; o; o >>= 1) v = min(v, __shfl_xor(v, o, 64));
    return v;
}

// ---------------- kernel 1: per-edge params + table repack (validated) ----------------
__global__ void prep_kernel(const float* __restrict__ verts,
                            const int*   __restrict__ edges,
                            const float* __restrict__ tab,
                            float*  __restrict__ ea,   float*  __restrict__ eb,
                            float4* __restrict__ pk14, float4* __restrict__ pk4,
                            float4* __restrict__ tb4) {
    int e = blockIdx.x * blockDim.x + threadIdx.x;
    if (e < NT) {
        const float* r = tab + 7 * e;
        tb4[e] = make_float4(r[3], r[4], r[5], r[6]);
    }
    if (e >= NE) return;
    int i0 = edges[2 * e + 0];
    int i1 = edges[2 * e + 1];
    float x0 = verts[3 * i0 + 0], y0 = verts[3 * i0 + 1];
    float x1 = verts[3 * i1 + 0], y1 = verts[3 * i1 + 1];
    float a = (y0 - y1) / (x0 - x1);
    float b = y0 - a * x0;
    ea[e] = a; eb[e] = b;
    pk14[e] = make_float4(fminf(x0, x1), fmaxf(x0, x1), a, b);        // phase-1 record
    pk4[e]  = make_float4(fminf(y0, y1), fmaxf(y0, y1), 1.0f / a, b); // phase-2 record
}

// ---------------- kernel 2: 8 points/block, 2 waves/point, LDS edge table ----------------
// 512 blocks x 1024 thr (16 waves), 2 blocks/CU -> 8 waves/SIMD.
__global__ __launch_bounds__(1024, 8) void point_kernel(
        const float*  __restrict__ verts,
        const int*    __restrict__ listAll,
        const float*  __restrict__ ea,   const float*  __restrict__ eb,
        const float4* __restrict__ pk14, const float4* __restrict__ pk4,
        const float4* __restrict__ tb4,
        float* __restrict__ mOut, int* __restrict__ vOut) {
    __shared__ float4 sE[NE];          // 64 KB edge params (ymn, ymx, 1/a, b)
    __shared__ int    sMI[16];
    __shared__ float  sA[16], sB[16], sSt[16][6], sPM[16];
    __shared__ float  sPX[NPB], sPY[NPB], sCY[NPB], sL1[NPB], sL2[NPB];
    __shared__ int    sVal[NPB];

    const int tid  = threadIdx.x;
    const int lane = tid & 63;
    const int w    = tid >> 6;        // wave 0..15
    const int pl   = w >> 1;          // point-in-block 0..7
    const int h    = w & 1;           // edge half 0..1
    const int pBase = blockIdx.x * NPB;
    const int p    = pBase + pl;

    // issue staging loads early (latency hides under phase 1)
    float4 r0 = pk4[tid];
    float4 r1 = pk4[1024 + tid];
    float4 r2 = pk4[2048 + tid];
    float4 r3 = pk4[3072 + tid];

    // ---- phase 1: first edge with px strictly inside (xmn,xmx), over my half ----
    {
        int vi = listAll[p];
        float px = verts[3 * vi + 0];
        float py = verts[3 * vi + 1];
        int minIdx = NE;
        float4 q4 = make_float4(0.f, 0.f, 0.f, 0.f);
        const int base = h * HALF;
        for (int it = 0; it < HALF / 64; ++it) {
            int e = base + it * 64 + lane;
            q4 = pk14[e];
            bool hit = (px > q4.x) && (px < q4.y);
            if (hit) minIdx = e;
            if (__any(hit)) break;
        }
        int mi = waveMinI(minIdx);
        float aH = __shfl(q4.z, mi & 63, 64);   // winning lane still holds its edge record
        float bH = __shfl(q4.w, mi & 63, 64);
        if (lane == 0) {
            sMI[w] = mi; sA[w] = aH; sB[w] = bH;
            if (h == 0) { sPX[pl] = px; sPY[pl] = py; }
        }
    }

    // ---- complete staging ----
    sE[tid]        = r0;
    sE[1024 + tid] = r1;
    sE[2048 + tid] = r2;
    sE[3072 + tid] = r3;
    __syncthreads();

    // ---- fold phase-1 halves: one thread per point ----
    if (tid < NPB) {
        int m0 = sMI[2 * tid], m1 = sMI[2 * tid + 1];
        float a_, b_;
        if (m0 < NE)      { a_ = sA[2 * tid];     b_ = sB[2 * tid]; }
        else if (m1 < NE) { a_ = sA[2 * tid + 1]; b_ = sB[2 * tid + 1]; }
        else              { a_ = ea[NE - 1];      b_ = eb[NE - 1]; }
        float px = sPX[tid], py = sPY[tid];
        float exposeY = a_ * px + b_;             // identical arithmetic to reference
        sCY[tid] = 0.5f * (py + exposeY);
        sL1[tid] = fabsf(py - exposeY);
    }
    __syncthreads();

    // ---- phase 2: my half of the edges for my point, from LDS (branchless) ----
    const float cy = sCY[pl];
    const float cx = sPX[pl];
    int   nAcc = 0, hasS = 0, hasI = 0;
    float xallmx = -SENTF, xallmn = SENTF;
    float xs = SENTF, xinf = -SENTF;
    #pragma unroll 8
    for (int it = 0; it < HALF / 64; ++it) {
        float4 q = sE[h * HALF + it * 64 + lane];   // (ymn, ymx, 1/a, b)
        bool  c  = (cy > q.x) && (cy < q.y);
        float xi = (cy - q.w) * q.z;                // identical arithmetic to validated path
        nAcc += c ? 1 : 0;
        xallmx = fmaxf(xallmx, c ? xi : -SENTF);
        xallmn = fminf(xallmn, c ? xi :  SENTF);
        bool sp  = c && (xi >= cx);
        bool in_ = c && (xi <  cx);
        xs   = fminf(xs,   sp  ? xi :  SENTF);
        xinf = fmaxf(xinf, in_ ? xi : -SENTF);
        hasS |= sp ? 1 : 0;
        hasI |= in_ ? 1 : 0;
    }
    int packed = nAcc | (hasS << 16) | (hasI << 24);
    packed = waveSumI(packed);
    xallmx = waveMaxF(xallmx);
    xallmn = waveMinF(xallmn);
    xs     = waveMinF(xs);
    xinf   = waveMaxF(xinf);
    if (lane == 0) {
        sSt[w][0] = xallmx; sSt[w][1] = xallmn;
        sSt[w][2] = xs;     sSt[w][3] = xinf;
        sSt[w][4] = __int_as_float(packed);
    }
    __syncthreads();

    // ---- fold the two halves per point: one thread per point ----
    if (tid < NPB) {
        int w0 = 2 * tid, w1 = 2 * tid + 1;
        float mxv = fmaxf(sSt[w0][0], sSt[w1][0]);
        float mnv = fminf(sSt[w0][1], sSt[w1][1]);
        float xsv = fminf(sSt[w0][2], sSt[w1][2]);
        float xfv = fmaxf(sSt[w0][3], sSt[w1][3]);
        int pk = __float_as_int(sSt[w0][4]) + __float_as_int(sSt[w1][4]);
        int n  = pk & 0xFFFF;
        int hS = (pk >> 16) & 0xFF;
        int hI = (pk >> 24) & 0xFF;
        bool valid = (n == 2) || ((n > 2) && (hS > 0) && (hI > 0));
        float dx = (n == 2) ? (mxv - mnv) : (xsv - xfv);
        sL2[tid]  = fabsf(dx);
        sVal[tid] = valid ? 1 : 0;
    }
    __syncthreads();

    // ---- table min: wave w -> point pl, table half h (validated float4 path) ----
    {
        float L1v = sL1[pl], L2v = sL2[pl];
        float d1  = fabsf(sCY[pl] - 1.0f);
        float d2  = fabsf(sPX[pl] - 1.0f);
        float pm = INFINITY;
        #pragma unroll
        for (int kk = 0; kk < NT / 128; ++kk) {
            float4 r = tb4[h * (NT / 2) + kk * 64 + lane];
            float al = fabsf(L1v - r.x) + fabsf(L2v - r.y) +
                       fabsf(d1 - r.z) + fabsf(d2 - r.w);
            pm = fminf(pm, al);
        }
        pm = waveMinF(pm);
        if (lane == 0) sPM[w] = pm;
    }
    __syncthreads();

    if (tid < NPB) {
        float pm = fminf(sPM[2 * tid], sPM[2 * tid + 1]);
        mOut[pBase + tid] = sVal[tid] ? pm : BIGF;
        vOut[pBase + tid] = sVal[tid];
    }
}

// ---------------- kernel 3: cummin + masked sum (validated) ----------------
__global__ __launch_bounds__(1024) void scan_kernel(const float* __restrict__ m,
                                                    const int*   __restrict__ valid,
                                                    float* __restrict__ out) {
    __shared__ float wAgg[16];
    __shared__ float wSum[16];
    int t = threadIdx.x;
    int lane = t & 63, wid = t >> 6;

    float v[4]; int vl[4];
    #pragma unroll
    for (int j = 0; j < 4; j++) { v[j] = m[4 * t + j]; vl[j] = valid[4 * t + j]; }
    float cmin = fminf(fminf(v[0], v[1]), fminf(v[2], v[3]));

    float inc = cmin;
    #pragma unroll
    for (int o = 1; o < 64; o <<= 1) {
        float u = __shfl_up(inc, o, 64);
        if (lane >= o) inc = fminf(inc, u);
    }
    if (lane == 63) wAgg[wid] = inc;
    __syncthreads();

    float wavePrefix = INFINITY;
    for (int i = 0; i < wid; i++) wavePrefix = fminf(wavePrefix, wAgg[i]);
    float excl = __shfl_up(inc, 1, 64);
    if (lane == 0) excl = INFINITY;
    float run = fminf(wavePrefix, excl);

    float sum = 0.0f;
    #pragma unroll
    for (int j = 0; j < 4; j++) {
        run = fminf(run, v[j]);
        if (vl[j]) sum += run;
    }
    #pragma unroll
    for (int o = 32; o; o >>= 1) sum += __shfl_xor(sum, o, 64);
    if (lane == 0) wSum[wid] = sum;
    __syncthreads();
    if (t == 0) {
        float s = 0.0f;
        for (int i = 0; i < 16; i++) s += wSum[i];
        out[0] = s;
    }
}

extern "C" void kernel_launch(void* const* d_in, const int* in_sizes, int n_in,
                              void* d_out, int out_size, void* d_ws, size_t ws_size,
                              hipStream_t stream) {
    const float* verts   = (const float*)d_in[0];
    const float* tab     = (const float*)d_in[1];
    const int*   edges   = (const int*)d_in[2];
    const int*   listAll = (const int*)d_in[3];

    char* ws = (char*)d_ws;
    float4* pk4  = (float4*)ws;                   ws += NE * sizeof(float4);
    float4* pk14 = (float4*)ws;                   ws += NE * sizeof(float4);
    float4* tb4  = (float4*)ws;                   ws += NT * sizeof(float4);
    float*  ea   = (float*)ws;                    ws += NE * sizeof(float);
    float*  eb   = (float*)ws;                    ws += NE * sizeof(float);
    float*  mArr = (float*)ws;                    ws += NP * sizeof(float);
    int*    vArr = (int*)ws;

    prep_kernel<<<(NE + 255) / 256, 256, 0, stream>>>(verts, edges, tab,
                                                      ea, eb, pk14, pk4, tb4);
    point_kernel<<<NP / NPB, 1024, 0, stream>>>(verts, listAll,
                                                ea, eb, pk14, pk4, tb4,
                                                mArr, vArr);
    scan_kernel<<<1, 1024, 0, stream>>>(mArr, vArr, (float*)d_out);
}